// Round 2
// baseline (198.602 us; speedup 1.0000x reference)
//
#include <hip/hip_runtime.h>
#include <hip/hip_bf16.h>

// Alpha2Assoc: fused single-pass over D with 3 running prefix products.
// Memory-bound: 134 MB read + 403 MB write. float4 (4 pixels/thread).

#define NUM_D 32
#define NUM_LAYERS 3
#define ALPHA_MIN 1e-4f

__device__ __forceinline__ void step(float a1, float& pr1, float& pr2, float& pr3,
                                     float& o1, float& o2, float& o3) {
    // layer 0: occ0 = 1
    float vis1 = pr1;
    o1 = vis1;                      // vis1 * occ0
    pr1 *= (1.0f - a1);
    float occ1 = 1.0f - vis1;
    // layer 1
    float a2 = a1 * occ1;
    float vis2 = pr2;
    o2 = vis2 * occ1;
    pr2 *= (1.0f - a2);
    float occ2 = 1.0f - vis2;
    // layer 2
    float a3 = a2 * occ2;
    float vis3 = pr3;
    o3 = vis3 * occ2;
    pr3 *= (1.0f - a3);
}

__global__ __launch_bounds__(256) void alpha2assoc_kernel(
    const float4* __restrict__ in,   // [B, D, 1, H, W] viewed as float4
    float4* __restrict__ out,        // [B, D, 3, H, W] viewed as float4
    int HW4,                         // H*W/4
    int nq)                          // B*H*W/4
{
    int t = blockIdx.x * blockDim.x + threadIdx.x;
    if (t >= nq) return;

    int b = t / HW4;
    int p = t - b * HW4;

    const float4* inb = in + (size_t)b * NUM_D * HW4 + p;
    float4* outb = out + (size_t)b * NUM_D * NUM_LAYERS * HW4 + p;

    float4 pr1 = {1.f, 1.f, 1.f, 1.f};
    float4 pr2 = {1.f, 1.f, 1.f, 1.f};
    float4 pr3 = {1.f, 1.f, 1.f, 1.f};

#pragma unroll
    for (int d = 0; d < NUM_D; ++d) {
        float4 av = inb[(size_t)d * HW4];
        float4 o1, o2, o3;
        step(fmaxf(av.x, ALPHA_MIN), pr1.x, pr2.x, pr3.x, o1.x, o2.x, o3.x);
        step(fmaxf(av.y, ALPHA_MIN), pr1.y, pr2.y, pr3.y, o1.y, o2.y, o3.y);
        step(fmaxf(av.z, ALPHA_MIN), pr1.z, pr2.z, pr3.z, o1.z, o2.z, o3.z);
        step(fmaxf(av.w, ALPHA_MIN), pr1.w, pr2.w, pr3.w, o1.w, o2.w, o3.w);
        outb[((size_t)d * NUM_LAYERS + 0) * HW4] = o1;
        outb[((size_t)d * NUM_LAYERS + 1) * HW4] = o2;
        outb[((size_t)d * NUM_LAYERS + 2) * HW4] = o3;
    }
}

extern "C" void kernel_launch(void* const* d_in, const int* in_sizes, int n_in,
                              void* d_out, int out_size, void* d_ws, size_t ws_size,
                              hipStream_t stream) {
    const float* in = (const float*)d_in[0];
    float* out = (float*)d_out;

    const int HW = 512 * 512;
    const int n = in_sizes[0];           // B*D*HW
    const int npix = n / NUM_D;          // B*HW
    const int HW4 = HW / 4;
    const int nq = npix / 4;

    int block = 256;
    int grid = (nq + block - 1) / block;
    alpha2assoc_kernel<<<grid, block, 0, stream>>>(
        (const float4*)in, (float4*)out, HW4, nq);
}

// Round 3
// 108.464 us; speedup vs baseline: 1.8310x; 1.8310x over previous
//
#include <hip/hip_runtime.h>
#include <hip/hip_bf16.h>

// Alpha2Assoc: fused single-pass over D (3 running prefix products, state = 3 regs).
// 1 pixel/thread, scalar coalesced dword accesses (R1's proven pattern),
// non-temporal stores for the 403 MB streaming output.

#define NUM_D 32
#define NUM_LAYERS 3
#define ALPHA_MIN 1e-4f

__global__ __launch_bounds__(256) void alpha2assoc_kernel(
    const float* __restrict__ in,   // [B, D, 1, H, W]
    float* __restrict__ out,        // [B, D, 3, H, W]
    int HW,                         // H*W
    int npix)                       // B*H*W
{
    int t = blockIdx.x * blockDim.x + threadIdx.x;
    if (t >= npix) return;

    int b = t / HW;
    int p = t - b * HW;

    const float* inb = in + (size_t)b * NUM_D * HW + p;
    float* outb = out + (size_t)b * NUM_D * NUM_LAYERS * HW + p;

    float pr1 = 1.0f, pr2 = 1.0f, pr3 = 1.0f;

#pragma unroll
    for (int d = 0; d < NUM_D; ++d) {
        float a1 = fmaxf(__builtin_nontemporal_load(&inb[(size_t)d * HW]), ALPHA_MIN);

        // layer 0 (occ0 == 1)
        float vis1 = pr1;
        float occ1 = 1.0f - vis1;
        // layer 1
        float a2 = a1 * occ1;
        float vis2 = pr2;
        float occ2 = 1.0f - vis2;
        // layer 2
        float a3 = a2 * occ2;
        float vis3 = pr3;

        float* ob = &outb[(size_t)d * NUM_LAYERS * HW];
        __builtin_nontemporal_store(vis1,        &ob[0]);
        __builtin_nontemporal_store(vis2 * occ1, &ob[HW]);
        __builtin_nontemporal_store(vis3 * occ2, &ob[2 * HW]);

        pr1 *= (1.0f - a1);
        pr2 *= (1.0f - a2);
        pr3 *= (1.0f - a3);
    }
}

extern "C" void kernel_launch(void* const* d_in, const int* in_sizes, int n_in,
                              void* d_out, int out_size, void* d_ws, size_t ws_size,
                              hipStream_t stream) {
    const float* in = (const float*)d_in[0];
    float* out = (float*)d_out;

    const int HW = 512 * 512;
    const int n = in_sizes[0];           // B*D*HW
    const int npix = n / NUM_D;          // B*HW

    int block = 256;
    int grid = (npix + block - 1) / block;
    alpha2assoc_kernel<<<grid, block, 0, stream>>>(in, out, HW, npix);
}